// Round 1
// 751.334 us; speedup vs baseline: 1.1143x; 1.1143x over previous
//
#include <hip/hip_runtime.h>
#include <hip/hip_bf16.h>
#include <math.h>

#define T 2048
#define HID 4096
#define NH 32
#define NKV 8
#define DH 128
#define QKV_N 6144
#define SCALE_F 0.08838834764831845f
#define NEGV -1e9f

typedef unsigned short u16t;
typedef __attribute__((ext_vector_type(8))) short bf8;
typedef __attribute__((ext_vector_type(4))) float f4;

__device__ __forceinline__ float bf2f(u16t x) {
  unsigned int u = ((unsigned int)x) << 16;
  return __builtin_bit_cast(float, u);
}
__device__ __forceinline__ u16t f2bf(float f) {
  unsigned int u = __builtin_bit_cast(unsigned int, f);
  u += 0x7fffu + ((u >> 16) & 1u);
  return (u16t)(u >> 16);
}

// Load 8 consecutive elements as bf16 from either a bf16 or f32 source (compile-time).
template <int F32>
__device__ __forceinline__ bf8 load8(const void* p, size_t idx) {
  if (F32) {
    const f4* fp = (const f4*)((const float*)p + idx);
    f4 a = fp[0], b = fp[1];
    bf8 r;
    r[0] = (short)f2bf(a[0]); r[1] = (short)f2bf(a[1]);
    r[2] = (short)f2bf(a[2]); r[3] = (short)f2bf(a[3]);
    r[4] = (short)f2bf(b[0]); r[5] = (short)f2bf(b[1]);
    r[6] = (short)f2bf(b[2]); r[7] = (short)f2bf(b[3]);
    return r;
  }
  return *(const bf8*)((const u16t*)p + idx);
}

// async 16B global -> LDS copy (dest must be linear: wave base + lane*16)
__device__ __forceinline__ void gl_lds16(const u16t* g, u16t* l) {
  __builtin_amdgcn_global_load_lds(
      (const __attribute__((address_space(1))) void*)g,
      (__attribute__((address_space(3))) void*)l, 16, 0, 0);
}

// ---------------- f32 -> bf16 bulk convert (8 elems/thread) -----------------
__global__ __launch_bounds__(256) void cvt_bf16(const float* __restrict__ in,
                                                u16t* __restrict__ out, int n8) {
  int i = blockIdx.x * 256 + threadIdx.x;
  if (i >= n8) return;
  const f4* fp = (const f4*)(in + (size_t)i * 8);
  f4 a = fp[0], b = fp[1];
  bf8 r;
  r[0] = (short)f2bf(a[0]); r[1] = (short)f2bf(a[1]);
  r[2] = (short)f2bf(a[2]); r[3] = (short)f2bf(a[3]);
  r[4] = (short)f2bf(b[0]); r[5] = (short)f2bf(b[1]);
  r[6] = (short)f2bf(b[2]); r[7] = (short)f2bf(b[3]);
  *(bf8*)(out + (size_t)i * 8) = r;
}

// ---------------- GEMM: C[M][N] = A[M][K] * B[N][K]^T ------------------------
// m97 structure: 128x128 tile, BK=64, 4 waves 2x2, linear LDS [128][64],
// global_load_lds width-16 staging, bf16 operands only. OUT32: output dtype.
template <int OUT32>
__global__ __launch_bounds__(256) void gemm_bt_bf(const u16t* __restrict__ A,
                                                  const u16t* __restrict__ B,
                                                  void* __restrict__ C, int N, int K) {
  __shared__ alignas(16) u16t As[128 * 64];
  __shared__ alignas(16) u16t Bs[128 * 64];
  const int tid = threadIdx.x;
  const int wave = tid >> 6, lane = tid & 63;
  const int l15 = lane & 15, quad = lane >> 4;
  // bijective XCD swizzle (requires nwg % 8 == 0; 768 and 512 both qualify)
  unsigned nwg = gridDim.x * gridDim.y;
  unsigned lin = blockIdx.y * gridDim.x + blockIdx.x;
  lin = (lin & 7) * (nwg >> 3) + (lin >> 3);
  const int bx = lin % gridDim.x, by = lin / gridDim.x;
  const int m0 = by * 128, n0 = bx * 128;
  const int wm = (wave & 1) * 64, wn = (wave >> 1) * 64;

  // staging coords: thread -> (row, 16B chunk); rows advance 32 per iter
  const int sr = tid >> 3, skc = (tid & 7) << 3;
  const u16t* Ag = A + (size_t)(m0 + sr) * K + skc;
  const u16t* Bg = B + (size_t)(n0 + sr) * K + skc;

  f4 acc[4][4];
#pragma unroll
  for (int i = 0; i < 4; i++)
#pragma unroll
    for (int j = 0; j < 4; j++) acc[i][j] = (f4){0.f, 0.f, 0.f, 0.f};

  for (int k0 = 0; k0 < K; k0 += 64) {
    __syncthreads();
#pragma unroll
    for (int i = 0; i < 4; i++) {
      int c = tid + 256 * i;  // linear LDS dest: base + lane*16 per wave
      gl_lds16(Ag + (size_t)(32 * i) * K + k0, &As[c * 8]);
      gl_lds16(Bg + (size_t)(32 * i) * K + k0, &Bs[c * 8]);
    }
    __syncthreads();  // compiler emits vmcnt(0) drain before s_barrier
#pragma unroll
    for (int kq = 0; kq < 2; kq++) {
      bf8 af[4], bfr[4];
#pragma unroll
      for (int mt = 0; mt < 4; mt++)
        af[mt] = *(const bf8*)&As[(wm + mt * 16 + l15) * 64 + kq * 32 + quad * 8];
#pragma unroll
      for (int nt = 0; nt < 4; nt++)
        bfr[nt] = *(const bf8*)&Bs[(wn + nt * 16 + l15) * 64 + kq * 32 + quad * 8];
#pragma unroll
      for (int mt = 0; mt < 4; mt++)
#pragma unroll
        for (int nt = 0; nt < 4; nt++)
          acc[mt][nt] = __builtin_amdgcn_mfma_f32_16x16x32_bf16(af[mt], bfr[nt], acc[mt][nt], 0, 0, 0);
    }
  }
#pragma unroll
  for (int mt = 0; mt < 4; mt++)
#pragma unroll
    for (int nt = 0; nt < 4; nt++)
#pragma unroll
      for (int r = 0; r < 4; r++) {
        int row = m0 + wm + mt * 16 + quad * 4 + r;
        int col = n0 + wn + nt * 16 + l15;
        if (OUT32)
          ((float*)C)[(size_t)row * N + col] = acc[mt][nt][r];
        else
          ((u16t*)C)[(size_t)row * N + col] = f2bf(acc[mt][nt][r]);
      }
}

// ---------------- Prep: RoPE q/k, gate, repack k_global ------------------------
__global__ __launch_bounds__(256) void prep_kernel(
    const int* __restrict__ positions, const u16t* __restrict__ qkv,
    const float* __restrict__ kg_in, const float* __restrict__ wg,
    const float* __restrict__ bg, u16t* __restrict__ Qr, u16t* __restrict__ Kl,
    u16t* __restrict__ KG, float* __restrict__ gate) {
  const int t = blockIdx.x, tid = threadIdx.x;
  const float pos = (float)positions[t];
  const u16t* row = qkv + (size_t)t * QKV_N;
  // Q rope + gate partial: pair p = h*64 + dp, 8 pairs/thread, head = tid/8
  float gp = 0.f;
#pragma unroll
  for (int i = 0; i < 8; i++) {
    int p = tid * 8 + i;
    int h = p >> 6, dp = p & 63;
    float invf = exp2f(-0.20762050593045702f * (float)dp);  // 10000^(-dp/64)
    float f = pos * invf;
    float c = cosf(f), s = sinf(f);
    float x1 = bf2f(row[h * DH + dp]);
    float x2 = bf2f(row[h * DH + dp + 64]);
    float o1 = x1 * c - x2 * s;
    float o2 = x2 * c + x1 * s;
    Qr[(size_t)t * HID + h * DH + dp] = f2bf(o1);
    Qr[(size_t)t * HID + h * DH + dp + 64] = f2bf(o2);
    gp += o1 * wg[h * DH + dp] + o2 * wg[h * DH + dp + 64];
  }
  gp += __shfl_xor(gp, 1, 64);
  gp += __shfl_xor(gp, 2, 64);
  gp += __shfl_xor(gp, 4, 64);
  if ((tid & 7) == 0) {
    int h = tid >> 3;
    gate[t * NH + h] = 1.f / (1.f + expf(-(gp + bg[h])));
  }
  // K rope: 512 pairs, 2/thread
  const u16t* krow = row + HID;
#pragma unroll
  for (int i = 0; i < 2; i++) {
    int p = tid * 2 + i;
    int g = p >> 6, dp = p & 63;
    float invf = exp2f(-0.20762050593045702f * (float)dp);
    float f = pos * invf;
    float c = cosf(f), s = sinf(f);
    float x1 = bf2f(krow[g * DH + dp]);
    float x2 = bf2f(krow[g * DH + dp + 64]);
    Kl[(size_t)g * T * DH + t * DH + dp] = f2bf(x1 * c - x2 * s);
    Kl[(size_t)g * T * DH + t * DH + dp + 64] = f2bf(x2 * c + x1 * s);
  }
  // repack k_global -> KG[g][t][d]
  {
    int d4 = tid * 4;
    int g = d4 >> 7, d = d4 & 127;
    const float* src = kg_in + (size_t)t * (NKV * DH) + d4;
    u16t* dst = KG + (size_t)g * T * DH + t * DH + d;
    dst[0] = f2bf(src[0]); dst[1] = f2bf(src[1]);
    dst[2] = f2bf(src[2]); dst[3] = f2bf(src[3]);
  }
}

// ---------------- Transpose: out[g][d][t] = in[t*istride + coff + g*128 + d] ---
template <int F32>
__global__ __launch_bounds__(256) void transpose_gd(const void* __restrict__ in,
                                                    u16t* __restrict__ out,
                                                    int istride, int coff) {
  __shared__ u16t tile[64][72];
  const int g = blockIdx.z;
  const int t0 = blockIdx.x * 64, d0 = blockIdx.y * 64;
  u16t* dst = out + (size_t)g * DH * T;
  const int tid = threadIdx.x;
#pragma unroll
  for (int i = 0; i < 2; i++) {
    int c = tid + 256 * i;           // 512 chunks
    int r = c >> 3, dch = (c & 7) << 3;
    size_t idx = (size_t)coff + g * DH + (size_t)(t0 + r) * istride + d0 + dch;
    *(bf8*)&tile[r][dch] = load8<F32>(in, idx);
  }
  __syncthreads();
#pragma unroll
  for (int i = 0; i < 2; i++) {
    int c = tid + 256 * i;
    int d = c >> 3, tch = (c & 7) << 3;
    bf8 v;
#pragma unroll
    for (int j = 0; j < 8; j++) v[j] = tile[tch + j][d];
    *(bf8*)&dst[(size_t)(d0 + d) * T + t0 + tch] = v;
  }
}

// ---------------- Flash attention (LOCAL=1: sliding window; 0: causal+combine) -
template <int LOCAL>
__global__ __launch_bounds__(256) void attn_kernel(
    const u16t* __restrict__ Qr, const u16t* __restrict__ Kbase,
    const u16t* __restrict__ VTbase, const float* __restrict__ gate,
    const u16t* __restrict__ oL, u16t* __restrict__ outp) {
  __shared__ u16t k_lds[64 * 136];   // [kv][d], pad 8
  __shared__ u16t v_lds[128 * 72];   // [d][kv], pad 8
  __shared__ u16t p_lds[128 * 72];   // [q][kv], pad 8
  const int h = blockIdx.x, qt = blockIdx.y;
  const int g = h >> 2;
  const int tid = threadIdx.x, wave = tid >> 6, lane = tid & 63;
  const int l15 = lane & 15, quad = lane >> 4;
  const int q0 = qt * 128 + wave * 32;
  const u16t* K = Kbase + (size_t)g * T * DH;   // [t][d]
  const u16t* VT = VTbase + (size_t)g * T * DH; // [d][t]

  bf8 qf[2][4];
#pragma unroll
  for (int mt = 0; mt < 2; mt++)
#pragma unroll
    for (int kq = 0; kq < 4; kq++)
      qf[mt][kq] = *(const bf8*)&Qr[(size_t)(q0 + mt * 16 + l15) * HID + h * DH + kq * 32 + quad * 8];

  f4 oacc[2][8];
  float m_st[2][4], l_st[2][4];
#pragma unroll
  for (int mt = 0; mt < 2; mt++) {
#pragma unroll
    for (int dt = 0; dt < 8; dt++) oacc[mt][dt] = (f4){0.f, 0.f, 0.f, 0.f};
#pragma unroll
    for (int r = 0; r < 4; r++) { m_st[mt][r] = -__builtin_inff(); l_st[mt][r] = 0.f; }
  }

  const int jend = 2 * qt + 2;
  const int jbeg = LOCAL ? (qt > 0 ? 2 * qt - 1 : 0) : 0;
  for (int j = jbeg; j < jend; j++) {
    const int kv0 = j * 64;
    __syncthreads();
#pragma unroll
    for (int i = 0; i < 4; i++) {
      int c = tid + 256 * i;  // 1024 chunks each
      int r = c >> 4, dch = (c & 15) << 3;
      *(bf8*)&k_lds[r * 136 + dch] = *(const bf8*)&K[(size_t)(kv0 + r) * DH + dch];
      int dd = c >> 3, kch = (c & 7) << 3;
      *(bf8*)&v_lds[dd * 72 + kch] = *(const bf8*)&VT[(size_t)dd * T + kv0 + kch];
    }
    __syncthreads();
    // S = Q K^T  (per wave: 32 q rows x 64 kv)
    f4 s[2][4];
#pragma unroll
    for (int nt = 0; nt < 4; nt++) {
      bf8 kb[4];
#pragma unroll
      for (int kq = 0; kq < 4; kq++)
        kb[kq] = *(const bf8*)&k_lds[(nt * 16 + l15) * 136 + kq * 32 + quad * 8];
#pragma unroll
      for (int mt = 0; mt < 2; mt++) {
        f4 a = (f4){0.f, 0.f, 0.f, 0.f};
#pragma unroll
        for (int kq = 0; kq < 4; kq++)
          a = __builtin_amdgcn_mfma_f32_16x16x32_bf16(qf[mt][kq], kb[kq], a, 0, 0, 0);
        s[mt][nt] = a;
      }
    }
    // scale + mask
#pragma unroll
    for (int mt = 0; mt < 2; mt++)
#pragma unroll
      for (int nt = 0; nt < 4; nt++)
#pragma unroll
        for (int r = 0; r < 4; r++) {
          float v = s[mt][nt][r] * SCALE_F;
          int qq = q0 + mt * 16 + quad * 4 + r;
          int kk = kv0 + nt * 16 + l15;
          bool ok = LOCAL ? (kk <= qq && kk >= qq - 63) : (kk <= qq);
          s[mt][nt][r] = ok ? v : NEGV;
        }
    // online softmax stats
    float alpha[2][4], mn[2][4], rs[2][4];
#pragma unroll
    for (int mt = 0; mt < 2; mt++)
#pragma unroll
      for (int r = 0; r < 4; r++) {
        float rm = fmaxf(fmaxf(s[mt][0][r], s[mt][1][r]), fmaxf(s[mt][2][r], s[mt][3][r]));
        rm = fmaxf(rm, __shfl_xor(rm, 1, 64));
        rm = fmaxf(rm, __shfl_xor(rm, 2, 64));
        rm = fmaxf(rm, __shfl_xor(rm, 4, 64));
        rm = fmaxf(rm, __shfl_xor(rm, 8, 64));
        float m2 = fmaxf(m_st[mt][r], rm);
        alpha[mt][r] = __expf(m_st[mt][r] - m2);
        m_st[mt][r] = m2;
        mn[mt][r] = m2;
        rs[mt][r] = 0.f;
      }
#pragma unroll
    for (int mt = 0; mt < 2; mt++)
#pragma unroll
      for (int nt = 0; nt < 4; nt++)
#pragma unroll
        for (int r = 0; r < 4; r++) {
          float p = __expf(s[mt][nt][r] - mn[mt][r]);
          rs[mt][r] += p;
          p_lds[(wave * 32 + mt * 16 + quad * 4 + r) * 72 + nt * 16 + l15] = f2bf(p);
        }
#pragma unroll
    for (int mt = 0; mt < 2; mt++)
#pragma unroll
      for (int r = 0; r < 4; r++) {
        float t0 = rs[mt][r];
        t0 += __shfl_xor(t0, 1, 64);
        t0 += __shfl_xor(t0, 2, 64);
        t0 += __shfl_xor(t0, 4, 64);
        t0 += __shfl_xor(t0, 8, 64);
        l_st[mt][r] = l_st[mt][r] * alpha[mt][r] + t0;
      }
#pragma unroll
    for (int mt = 0; mt < 2; mt++)
#pragma unroll
      for (int dt = 0; dt < 8; dt++) {
        f4 o = oacc[mt][dt];
        o[0] *= alpha[mt][0]; o[1] *= alpha[mt][1];
        o[2] *= alpha[mt][2]; o[3] *= alpha[mt][3];
        oacc[mt][dt] = o;
      }
    __syncthreads();
    // PV: O += P V   (P a-frags from own wave's rows)
    bf8 pa[2][2];
#pragma unroll
    for (int mt = 0; mt < 2; mt++)
#pragma unroll
      for (int kq = 0; kq < 2; kq++)
        pa[mt][kq] = *(const bf8*)&p_lds[(wave * 32 + mt * 16 + l15) * 72 + kq * 32 + quad * 8];
#pragma unroll
    for (int dt = 0; dt < 8; dt++) {
      bf8 vb[2];
#pragma unroll
      for (int kq = 0; kq < 2; kq++)
        vb[kq] = *(const bf8*)&v_lds[(dt * 16 + l15) * 72 + kq * 32 + quad * 8];
#pragma unroll
      for (int mt = 0; mt < 2; mt++) {
        oacc[mt][dt] = __builtin_amdgcn_mfma_f32_16x16x32_bf16(pa[mt][0], vb[0], oacc[mt][dt], 0, 0, 0);
        oacc[mt][dt] = __builtin_amdgcn_mfma_f32_16x16x32_bf16(pa[mt][1], vb[1], oacc[mt][dt], 0, 0, 0);
      }
    }
  }
  // epilogue
#pragma unroll
  for (int mt = 0; mt < 2; mt++)
#pragma unroll
    for (int r = 0; r < 4; r++) {
      int tq = q0 + mt * 16 + quad * 4 + r;
      float inv_l = 1.f / l_st[mt][r];
      if (LOCAL) {
#pragma unroll
        for (int dt = 0; dt < 8; dt++) {
          int col = dt * 16 + l15;
          outp[(size_t)tq * HID + h * DH + col] = f2bf(oacc[mt][dt][r] * inv_l);
        }
      } else {
        float gt = gate[tq * NH + h];
#pragma unroll
        for (int dt = 0; dt < 8; dt++) {
          int col = dt * 16 + l15;
          float ov = oacc[mt][dt][r] * inv_l;
          float ol = bf2f(oL[(size_t)tq * HID + h * DH + col]);
          outp[(size_t)tq * HID + h * DH + col] = f2bf(ov * gt + ol * (1.f - gt));
        }
      }
    }
}

extern "C" void kernel_launch(void* const* d_in, const int* in_sizes, int n_in,
                              void* d_out, int out_size, void* d_ws, size_t ws_size,
                              hipStream_t stream) {
  (void)in_sizes; (void)n_in; (void)out_size; (void)ws_size;
  const int* positions = (const int*)d_in[0];
  const float* hidden = (const float*)d_in[1];    // f32 [T][HID]
  const float* k_global = (const float*)d_in[2];  // f32 [T][NKV][DH]
  const void* v_global = d_in[3];      // f32 [T][NKV][DH]
  const float* w_qkv = (const float*)d_in[4];     // f32 [QKV_N][HID]
  const float* w_o = (const float*)d_in[5];       // f32 [HID][HID]
  const float* w_gate = (const float*)d_in[6];    // f32 [NH][DH]
  const float* b_gate = (const float*)d_in[7];    // f32 [NH]
  float* out = (float*)d_out;          // f32 [T][HID]

  char* ws = (char*)d_ws;
  size_t off = 0;
  u16t* qkv = (u16t*)(ws + off); off += (size_t)T * QKV_N * 2;
  u16t* Qr  = (u16t*)(ws + off); off += (size_t)T * HID * 2;
  u16t* Kl  = (u16t*)(ws + off); off += (size_t)NKV * T * DH * 2;
  u16t* KG  = (u16t*)(ws + off); off += (size_t)NKV * T * DH * 2;
  u16t* VlT = (u16t*)(ws + off); off += (size_t)NKV * T * DH * 2;
  u16t* VGT = (u16t*)(ws + off); off += (size_t)NKV * T * DH * 2;
  float* gateb = (float*)(ws + off); off += (size_t)T * NH * 4;
  u16t* out_l = (u16t*)(ws + off); off += (size_t)T * HID * 2;
  u16t* out_c = (u16t*)(ws + off); off += (size_t)T * HID * 2;
  // bf16 weight scratch. hid_bf + wqkv_bf live only during GEMM1;
  // wo_bf (33.5MB) aliases that region (67MB) afterwards.
  u16t* hid_bf  = (u16t*)(ws + off);
  u16t* wqkv_bf = (u16t*)(ws + off + (size_t)T * HID * 2);
  u16t* wo_bf   = hid_bf;

  // 0) convert f32 operands to bf16 once (identical rounding to old in-GEMM path)
  cvt_bf16<<<(T * HID / 8) / 256, 256, 0, stream>>>(hidden, hid_bf, T * HID / 8);
  cvt_bf16<<<(QKV_N * HID / 8) / 256, 256, 0, stream>>>(w_qkv, wqkv_bf, QKV_N * HID / 8);
  // 1) qkv = hidden @ w_qkv^T   (bf16 in, bf16 out)
  gemm_bt_bf<0><<<dim3(QKV_N / 128, T / 128), 256, 0, stream>>>(hid_bf, wqkv_bf, qkv, QKV_N, HID);
  // 1b) convert w_o (aliases hid_bf region — GEMM1 is done with it, stream-ordered)
  cvt_bf16<<<(HID * HID / 8) / 256, 256, 0, stream>>>(w_o, wo_bf, HID * HID / 8);
  // 2) rope q/k, gate, repack k_global
  prep_kernel<<<T, 256, 0, stream>>>(positions, qkv, k_global, w_gate, b_gate, Qr, Kl, KG, gateb);
  // 3) transpose V's to [g][d][t]
  transpose_gd<0><<<dim3(T / 64, DH / 64, NKV), 256, 0, stream>>>(qkv, VlT, QKV_N, HID + NKV * DH);
  transpose_gd<1><<<dim3(T / 64, DH / 64, NKV), 256, 0, stream>>>(v_global, VGT, NKV * DH, 0);
  // 4) local sliding-window attention -> out_l
  attn_kernel<1><<<dim3(NH, T / 128), 256, 0, stream>>>(Qr, Kl, VlT, nullptr, nullptr, out_l);
  // 5) global causal attention + gate-combine -> out_c
  attn_kernel<0><<<dim3(NH, T / 128), 256, 0, stream>>>(Qr, KG, VGT, gateb, out_l, out_c);
  // 6) final = out_c @ w_o^T    (bf16 in, f32 out)
  gemm_bt_bf<1><<<dim3(HID / 128, T / 128), 256, 0, stream>>>(out_c, wo_bf, out, HID, HID);
}

// Round 2
// 706.520 us; speedup vs baseline: 1.1849x; 1.0634x over previous
//
#include <hip/hip_runtime.h>
#include <hip/hip_bf16.h>
#include <math.h>

#define T 2048
#define HID 4096
#define NH 32
#define NKV 8
#define DH 128
#define QKV_N 6144
#define SCALE_F 0.08838834764831845f
#define NEGV -1e9f

typedef unsigned short u16t;
typedef __attribute__((ext_vector_type(8))) short bf8;
typedef __attribute__((ext_vector_type(4))) float f4;

__device__ __forceinline__ float bf2f(u16t x) {
  unsigned int u = ((unsigned int)x) << 16;
  return __builtin_bit_cast(float, u);
}
__device__ __forceinline__ u16t f2bf(float f) {
  unsigned int u = __builtin_bit_cast(unsigned int, f);
  u += 0x7fffu + ((u >> 16) & 1u);
  return (u16t)(u >> 16);
}

template <int F32>
__device__ __forceinline__ bf8 load8(const void* p, size_t idx) {
  if (F32) {
    const f4* fp = (const f4*)((const float*)p + idx);
    f4 a = fp[0], b = fp[1];
    bf8 r;
    r[0] = (short)f2bf(a[0]); r[1] = (short)f2bf(a[1]);
    r[2] = (short)f2bf(a[2]); r[3] = (short)f2bf(a[3]);
    r[4] = (short)f2bf(b[0]); r[5] = (short)f2bf(b[1]);
    r[6] = (short)f2bf(b[2]); r[7] = (short)f2bf(b[3]);
    return r;
  }
  return *(const bf8*)((const u16t*)p + idx);
}

// async 16B global -> LDS copy (dest must be linear: wave base + lane*16)
__device__ __forceinline__ void gl_lds16(const u16t* g, u16t* l) {
  __builtin_amdgcn_global_load_lds(
      (const __attribute__((address_space(1))) void*)g,
      (__attribute__((address_space(3))) void*)l, 16, 0, 0);
}

#define BARR() __builtin_amdgcn_s_barrier()
#define LGKM0() asm volatile("s_waitcnt lgkmcnt(0)" ::: "memory")
#define VM4() asm volatile("s_waitcnt vmcnt(4)" ::: "memory")
#define VM2() asm volatile("s_waitcnt vmcnt(2)" ::: "memory")
#define VM0() asm volatile("s_waitcnt vmcnt(0)" ::: "memory")

// ---------------- f32 -> bf16 bulk convert (8 elems/thread) -----------------
__global__ __launch_bounds__(256) void cvt_bf16(const float* __restrict__ in,
                                                u16t* __restrict__ out, int n8) {
  int i = blockIdx.x * 256 + threadIdx.x;
  if (i >= n8) return;
  const f4* fp = (const f4*)(in + (size_t)i * 8);
  f4 a = fp[0], b = fp[1];
  bf8 r;
  r[0] = (short)f2bf(a[0]); r[1] = (short)f2bf(a[1]);
  r[2] = (short)f2bf(a[2]); r[3] = (short)f2bf(a[3]);
  r[4] = (short)f2bf(b[0]); r[5] = (short)f2bf(b[1]);
  r[6] = (short)f2bf(b[2]); r[7] = (short)f2bf(b[3]);
  *(bf8*)(out + (size_t)i * 8) = r;
}

// ---------------- 256x256 8-phase GEMM: C[M][N] = A[M][K] * B[N][K]^T --------
// 8 waves (2M x 4N interleaved), BK=64, double-buffered half-tiles, counted
// vmcnt, XOR chunk-swizzled LDS (swizzle on BOTH gload source and ds_read).

// Stage one 128x64 half-tile. G points at the half's first row. Thread c
// (c = tid + 512*i) fills LDS bytes [c*16, c*16+16); data source is global
// chunk (c&7)^(row&7) so that swizzled reads recover the right data.
__device__ __forceinline__ void stage_ht(const u16t* __restrict__ G, int K,
                                         int k0, u16t* lds, int tid) {
#pragma unroll
  for (int i = 0; i < 2; i++) {
    int c = tid + 512 * i;
    int r = c >> 3;
    int sc = (c & 7) ^ (r & 7);
    gl_lds16(G + (size_t)r * K + k0 + sc * 8, lds + c * 8);
  }
}

// Load NF fragment rows (stride RS) x 2 k-quads from a swizzled half-tile.
template <int NF, int RS>
__device__ __forceinline__ void ld_fr(bf8 (*f)[2], const u16t* buf, int rb, int quad) {
#pragma unroll
  for (int i = 0; i < NF; i++)
#pragma unroll
    for (int kq = 0; kq < 2; kq++) {
      int r = rb + i * RS;
      int ch = (kq * 4 + quad) ^ (r & 7);
      f[i][kq] = *(const bf8*)&buf[r * 64 + ch * 8];
    }
}

template <int QA, int QB>
__device__ __forceinline__ void mfma_quad(f4 (*acc)[4], const bf8 (*af)[2],
                                          const bf8 (*bf_)[2]) {
#pragma unroll
  for (int m = 0; m < 4; m++)
#pragma unroll
    for (int n = 0; n < 2; n++)
#pragma unroll
      for (int kq = 0; kq < 2; kq++)
        acc[QA * 4 + m][QB * 2 + n] = __builtin_amdgcn_mfma_f32_16x16x32_bf16(
            af[m][kq], bf_[n][kq], acc[QA * 4 + m][QB * 2 + n], 0, 0, 0);
}

template <int OUT32>
__global__ __launch_bounds__(512, 2) void gemm256(const u16t* __restrict__ A,
                                                  const u16t* __restrict__ B,
                                                  void* __restrict__ C, int N, int K) {
  __shared__ alignas(16) u16t As[2][2][128 * 64];
  __shared__ alignas(16) u16t Bs[2][2][128 * 64];
  const int tid = threadIdx.x;
  const int wave = tid >> 6, lane = tid & 63;
  const int l15 = lane & 15, quad = lane >> 4;
  const int wm = wave >> 2, wn = wave & 3;

  // bijective XCD swizzle (nwg % 8 == 0 for both GEMMs: 192, 128)
  unsigned nwg = gridDim.x * gridDim.y;
  unsigned lin = blockIdx.y * gridDim.x + blockIdx.x;
  lin = (lin & 7) * (nwg >> 3) + (lin >> 3);
  const int bx = lin % gridDim.x, by = lin / gridDim.x;
  const int m0 = by * 256, n0 = bx * 256;

  const u16t* A0p = A + (size_t)m0 * K;
  const u16t* A1p = A0p + (size_t)128 * K;
  const u16t* B0p = B + (size_t)n0 * K;
  const u16t* B1p = B0p + (size_t)128 * K;

  const int NT = K >> 6;

  // prologue: stage K-tile 0 (consumption order), then wait oldest 2 HTs
  stage_ht(A0p, K, 0, &As[0][0][0], tid);
  stage_ht(B0p, K, 0, &Bs[0][0][0], tid);
  stage_ht(B1p, K, 0, &Bs[0][1][0], tid);
  stage_ht(A1p, K, 0, &As[0][1][0], tid);

  f4 acc[8][4];
#pragma unroll
  for (int i = 0; i < 8; i++)
#pragma unroll
    for (int j = 0; j < 4; j++) acc[i][j] = (f4){0.f, 0.f, 0.f, 0.f};

  VM4();   // A0(0), B0(0) landed (B1, A1 may be in flight)
  BARR();

  bf8 af[4][2], b0f[2][2], b1f[2][2];
  const int ra = wm * 16 + l15;
  const int rb = wn * 16 + l15;

#pragma unroll 1
  for (int t = 0; t < NT; ++t) {
    const int cur = t & 1, nxt = cur ^ 1;
    const int kn = (t + 1) << 6;
    const bool st = (t + 1) < NT;
    // ---- phase 0: quadrant (A-half0, B-half0); 12 ds_reads; stage A0(t+1)
    ld_fr<4, 32>(af, &As[cur][0][0], ra, quad);
    ld_fr<2, 64>(b0f, &Bs[cur][0][0], rb, quad);
    if (st) stage_ht(A0p, K, kn, &As[nxt][0][0], tid);
    BARR(); LGKM0();
    __builtin_amdgcn_s_setprio(1);
    mfma_quad<0, 0>(acc, af, b0f);
    __builtin_amdgcn_s_setprio(0);
    if (st) { VM4(); } else { VM2(); }  // protect ph1's B1(t) reads
    BARR();
    // ---- phase 1: (A0, B1); 4 ds_reads; stage B0(t+1)
    ld_fr<2, 64>(b1f, &Bs[cur][1][0], rb, quad);
    if (st) stage_ht(B0p, K, kn, &Bs[nxt][0][0], tid);
    BARR(); LGKM0();
    __builtin_amdgcn_s_setprio(1);
    mfma_quad<0, 1>(acc, af, b1f);
    __builtin_amdgcn_s_setprio(0);
    if (st) { VM4(); } else { VM0(); }  // protect ph2's A1(t) reads
    BARR();
    // ---- phase 2: (A1, B1); 8 ds_reads; stage B1(t+1)
    ld_fr<4, 32>(af, &As[cur][1][0], ra, quad);
    if (st) stage_ht(B1p, K, kn, &Bs[nxt][1][0], tid);
    BARR(); LGKM0();
    __builtin_amdgcn_s_setprio(1);
    mfma_quad<1, 1>(acc, af, b1f);
    __builtin_amdgcn_s_setprio(0);
    BARR();                              // ph3 reads nothing: no vmcnt
    // ---- phase 3: (A1, B0); 0 ds_reads; stage A1(t+1)
    if (st) stage_ht(A1p, K, kn, &As[nxt][1][0], tid);
    BARR();
    __builtin_amdgcn_s_setprio(1);
    mfma_quad<1, 0>(acc, af, b0f);
    __builtin_amdgcn_s_setprio(0);
    if (st) { VM4(); }                   // protect next tile's A0,B0 reads
    BARR();
  }

  // epilogue: interleaved fragment map — row = m0+fm*32+wm*16, col = n0+fn*64+wn*16
#pragma unroll
  for (int fm = 0; fm < 8; fm++)
#pragma unroll
    for (int fn = 0; fn < 4; fn++)
#pragma unroll
      for (int r = 0; r < 4; r++) {
        int row = m0 + fm * 32 + wm * 16 + quad * 4 + r;
        int col = n0 + fn * 64 + wn * 16 + l15;
        if (OUT32)
          ((float*)C)[(size_t)row * N + col] = acc[fm][fn][r];
        else
          ((u16t*)C)[(size_t)row * N + col] = f2bf(acc[fm][fn][r]);
      }
}

// ---------------- Prep: RoPE q/k, gate, repack k_global ------------------------
__global__ __launch_bounds__(256) void prep_kernel(
    const int* __restrict__ positions, const u16t* __restrict__ qkv,
    const float* __restrict__ kg_in, const float* __restrict__ wg,
    const float* __restrict__ bg, u16t* __restrict__ Qr, u16t* __restrict__ Kl,
    u16t* __restrict__ KG, float* __restrict__ gate) {
  const int t = blockIdx.x, tid = threadIdx.x;
  const float pos = (float)positions[t];
  const u16t* row = qkv + (size_t)t * QKV_N;
  float gp = 0.f;
#pragma unroll
  for (int i = 0; i < 8; i++) {
    int p = tid * 8 + i;
    int h = p >> 6, dp = p & 63;
    float invf = exp2f(-0.20762050593045702f * (float)dp);
    float f = pos * invf;
    float c = cosf(f), s = sinf(f);
    float x1 = bf2f(row[h * DH + dp]);
    float x2 = bf2f(row[h * DH + dp + 64]);
    float o1 = x1 * c - x2 * s;
    float o2 = x2 * c + x1 * s;
    Qr[(size_t)t * HID + h * DH + dp] = f2bf(o1);
    Qr[(size_t)t * HID + h * DH + dp + 64] = f2bf(o2);
    gp += o1 * wg[h * DH + dp] + o2 * wg[h * DH + dp + 64];
  }
  gp += __shfl_xor(gp, 1, 64);
  gp += __shfl_xor(gp, 2, 64);
  gp += __shfl_xor(gp, 4, 64);
  if ((tid & 7) == 0) {
    int h = tid >> 3;
    gate[t * NH + h] = 1.f / (1.f + expf(-(gp + bg[h])));
  }
  const u16t* krow = row + HID;
#pragma unroll
  for (int i = 0; i < 2; i++) {
    int p = tid * 2 + i;
    int g = p >> 6, dp = p & 63;
    float invf = exp2f(-0.20762050593045702f * (float)dp);
    float f = pos * invf;
    float c = cosf(f), s = sinf(f);
    float x1 = bf2f(krow[g * DH + dp]);
    float x2 = bf2f(krow[g * DH + dp + 64]);
    Kl[(size_t)g * T * DH + t * DH + dp] = f2bf(x1 * c - x2 * s);
    Kl[(size_t)g * T * DH + t * DH + dp + 64] = f2bf(x2 * c + x1 * s);
  }
  {
    int d4 = tid * 4;
    int g = d4 >> 7, d = d4 & 127;
    const float* src = kg_in + (size_t)t * (NKV * DH) + d4;
    u16t* dst = KG + (size_t)g * T * DH + t * DH + d;
    dst[0] = f2bf(src[0]); dst[1] = f2bf(src[1]);
    dst[2] = f2bf(src[2]); dst[3] = f2bf(src[3]);
  }
}

// ---------------- Transpose: out[g][d][t] = in[t*istride + coff + g*128 + d] ---
template <int F32>
__global__ __launch_bounds__(256) void transpose_gd(const void* __restrict__ in,
                                                    u16t* __restrict__ out,
                                                    int istride, int coff) {
  __shared__ u16t tile[64][72];
  const int g = blockIdx.z;
  const int t0 = blockIdx.x * 64, d0 = blockIdx.y * 64;
  u16t* dst = out + (size_t)g * DH * T;
  const int tid = threadIdx.x;
#pragma unroll
  for (int i = 0; i < 2; i++) {
    int c = tid + 256 * i;
    int r = c >> 3, dch = (c & 7) << 3;
    size_t idx = (size_t)coff + g * DH + (size_t)(t0 + r) * istride + d0 + dch;
    *(bf8*)&tile[r][dch] = load8<F32>(in, idx);
  }
  __syncthreads();
#pragma unroll
  for (int i = 0; i < 2; i++) {
    int c = tid + 256 * i;
    int d = c >> 3, tch = (c & 7) << 3;
    bf8 v;
#pragma unroll
    for (int j = 0; j < 8; j++) v[j] = tile[tch + j][d];
    *(bf8*)&dst[(size_t)(d0 + d) * T + t0 + tch] = v;
  }
}

// ---------------- Flash attention (LOCAL=1: sliding window; 0: causal+combine) -
template <int LOCAL>
__global__ __launch_bounds__(256) void attn_kernel(
    const u16t* __restrict__ Qr, const u16t* __restrict__ Kbase,
    const u16t* __restrict__ VTbase, const float* __restrict__ gate,
    const u16t* __restrict__ oL, u16t* __restrict__ outp) {
  __shared__ u16t k_lds[64 * 136];
  __shared__ u16t v_lds[128 * 72];
  __shared__ u16t p_lds[128 * 72];
  const int h = blockIdx.x, qt = blockIdx.y;
  const int g = h >> 2;
  const int tid = threadIdx.x, wave = tid >> 6, lane = tid & 63;
  const int l15 = lane & 15, quad = lane >> 4;
  const int q0 = qt * 128 + wave * 32;
  const u16t* K = Kbase + (size_t)g * T * DH;
  const u16t* VT = VTbase + (size_t)g * T * DH;

  bf8 qf[2][4];
#pragma unroll
  for (int mt = 0; mt < 2; mt++)
#pragma unroll
    for (int kq = 0; kq < 4; kq++)
      qf[mt][kq] = *(const bf8*)&Qr[(size_t)(q0 + mt * 16 + l15) * HID + h * DH + kq * 32 + quad * 8];

  f4 oacc[2][8];
  float m_st[2][4], l_st[2][4];
#pragma unroll
  for (int mt = 0; mt < 2; mt++) {
#pragma unroll
    for (int dt = 0; dt < 8; dt++) oacc[mt][dt] = (f4){0.f, 0.f, 0.f, 0.f};
#pragma unroll
    for (int r = 0; r < 4; r++) { m_st[mt][r] = -__builtin_inff(); l_st[mt][r] = 0.f; }
  }

  const int jend = 2 * qt + 2;
  const int jbeg = LOCAL ? (qt > 0 ? 2 * qt - 1 : 0) : 0;
  for (int j = jbeg; j < jend; j++) {
    const int kv0 = j * 64;
    __syncthreads();
#pragma unroll
    for (int i = 0; i < 4; i++) {
      int c = tid + 256 * i;
      int r = c >> 4, dch = (c & 15) << 3;
      *(bf8*)&k_lds[r * 136 + dch] = *(const bf8*)&K[(size_t)(kv0 + r) * DH + dch];
      int dd = c >> 3, kch = (c & 7) << 3;
      *(bf8*)&v_lds[dd * 72 + kch] = *(const bf8*)&VT[(size_t)dd * T + kv0 + kch];
    }
    __syncthreads();
    f4 s[2][4];
#pragma unroll
    for (int nt = 0; nt < 4; nt++) {
      bf8 kb[4];
#pragma unroll
      for (int kq = 0; kq < 4; kq++)
        kb[kq] = *(const bf8*)&k_lds[(nt * 16 + l15) * 136 + kq * 32 + quad * 8];
#pragma unroll
      for (int mt = 0; mt < 2; mt++) {
        f4 a = (f4){0.f, 0.f, 0.f, 0.f};
#pragma unroll
        for (int kq = 0; kq < 4; kq++)
          a = __builtin_amdgcn_mfma_f32_16x16x32_bf16(qf[mt][kq], kb[kq], a, 0, 0, 0);
        s[mt][nt] = a;
      }
    }
#pragma unroll
    for (int mt = 0; mt < 2; mt++)
#pragma unroll
      for (int nt = 0; nt < 4; nt++)
#pragma unroll
        for (int r = 0; r < 4; r++) {
          float v = s[mt][nt][r] * SCALE_F;
          int qq = q0 + mt * 16 + quad * 4 + r;
          int kk = kv0 + nt * 16 + l15;
          bool ok = LOCAL ? (kk <= qq && kk >= qq - 63) : (kk <= qq);
          s[mt][nt][r] = ok ? v : NEGV;
        }
    float alpha[2][4], mn[2][4], rs[2][4];
#pragma unroll
    for (int mt = 0; mt < 2; mt++)
#pragma unroll
      for (int r = 0; r < 4; r++) {
        float rm = fmaxf(fmaxf(s[mt][0][r], s[mt][1][r]), fmaxf(s[mt][2][r], s[mt][3][r]));
        rm = fmaxf(rm, __shfl_xor(rm, 1, 64));
        rm = fmaxf(rm, __shfl_xor(rm, 2, 64));
        rm = fmaxf(rm, __shfl_xor(rm, 4, 64));
        rm = fmaxf(rm, __shfl_xor(rm, 8, 64));
        float m2 = fmaxf(m_st[mt][r], rm);
        alpha[mt][r] = __expf(m_st[mt][r] - m2);
        m_st[mt][r] = m2;
        mn[mt][r] = m2;
        rs[mt][r] = 0.f;
      }
#pragma unroll
    for (int mt = 0; mt < 2; mt++)
#pragma unroll
      for (int nt = 0; nt < 4; nt++)
#pragma unroll
        for (int r = 0; r < 4; r++) {
          float p = __expf(s[mt][nt][r] - mn[mt][r]);
          rs[mt][r] += p;
          p_lds[(wave * 32 + mt * 16 + quad * 4 + r) * 72 + nt * 16 + l15] = f2bf(p);
        }
#pragma unroll
    for (int mt = 0; mt < 2; mt++)
#pragma unroll
      for (int r = 0; r < 4; r++) {
        float t0 = rs[mt][r];
        t0 += __shfl_xor(t0, 1, 64);
        t0 += __shfl_xor(t0, 2, 64);
        t0 += __shfl_xor(t0, 4, 64);
        t0 += __shfl_xor(t0, 8, 64);
        l_st[mt][r] = l_st[mt][r] * alpha[mt][r] + t0;
      }
#pragma unroll
    for (int mt = 0; mt < 2; mt++)
#pragma unroll
      for (int dt = 0; dt < 8; dt++) {
        f4 o = oacc[mt][dt];
        o[0] *= alpha[mt][0]; o[1] *= alpha[mt][1];
        o[2] *= alpha[mt][2]; o[3] *= alpha[mt][3];
        oacc[mt][dt] = o;
      }
    __syncthreads();
    bf8 pa[2][2];
#pragma unroll
    for (int mt = 0; mt < 2; mt++)
#pragma unroll
      for (int kq = 0; kq < 2; kq++)
        pa[mt][kq] = *(const bf8*)&p_lds[(wave * 32 + mt * 16 + l15) * 72 + kq * 32 + quad * 8];
#pragma unroll
    for (int dt = 0; dt < 8; dt++) {
      bf8 vb[2];
#pragma unroll
      for (int kq = 0; kq < 2; kq++)
        vb[kq] = *(const bf8*)&v_lds[(dt * 16 + l15) * 72 + kq * 32 + quad * 8];
#pragma unroll
      for (int mt = 0; mt < 2; mt++) {
        oacc[mt][dt] = __builtin_amdgcn_mfma_f32_16x16x32_bf16(pa[mt][0], vb[0], oacc[mt][dt], 0, 0, 0);
        oacc[mt][dt] = __builtin_amdgcn_mfma_f32_16x16x32_bf16(pa[mt][1], vb[1], oacc[mt][dt], 0, 0, 0);
      }
    }
  }
#pragma unroll
  for (int mt = 0; mt < 2; mt++)
#pragma unroll
    for (int r = 0; r < 4; r++) {
      int tq = q0 + mt * 16 + quad * 4 + r;
      float inv_l = 1.f / l_st[mt][r];
      if (LOCAL) {
#pragma unroll
        for (int dt = 0; dt < 8; dt++) {
          int col = dt * 16 + l15;
          outp[(size_t)tq * HID + h * DH + col] = f2bf(oacc[mt][dt][r] * inv_l);
        }
      } else {
        float gt = gate[tq * NH + h];
#pragma unroll
        for (int dt = 0; dt < 8; dt++) {
          int col = dt * 16 + l15;
          float ov = oacc[mt][dt][r] * inv_l;
          float ol = bf2f(oL[(size_t)tq * HID + h * DH + col]);
          outp[(size_t)tq * HID + h * DH + col] = f2bf(ov * gt + ol * (1.f - gt));
        }
      }
    }
}

extern "C" void kernel_launch(void* const* d_in, const int* in_sizes, int n_in,
                              void* d_out, int out_size, void* d_ws, size_t ws_size,
                              hipStream_t stream) {
  (void)in_sizes; (void)n_in; (void)out_size; (void)ws_size;
  const int* positions = (const int*)d_in[0];
  const float* hidden = (const float*)d_in[1];
  const float* k_global = (const float*)d_in[2];
  const void* v_global = d_in[3];
  const float* w_qkv = (const float*)d_in[4];
  const float* w_o = (const float*)d_in[5];
  const float* w_gate = (const float*)d_in[6];
  const float* b_gate = (const float*)d_in[7];
  float* out = (float*)d_out;

  char* ws = (char*)d_ws;
  size_t off = 0;
  u16t* qkv = (u16t*)(ws + off); off += (size_t)T * QKV_N * 2;
  u16t* Qr  = (u16t*)(ws + off); off += (size_t)T * HID * 2;
  u16t* Kl  = (u16t*)(ws + off); off += (size_t)NKV * T * DH * 2;
  u16t* KG  = (u16t*)(ws + off); off += (size_t)NKV * T * DH * 2;
  u16t* VlT = (u16t*)(ws + off); off += (size_t)NKV * T * DH * 2;
  u16t* VGT = (u16t*)(ws + off); off += (size_t)NKV * T * DH * 2;
  float* gateb = (float*)(ws + off); off += (size_t)T * NH * 4;
  u16t* out_l = (u16t*)(ws + off); off += (size_t)T * HID * 2;
  u16t* out_c = (u16t*)(ws + off); off += (size_t)T * HID * 2;
  u16t* hid_bf  = (u16t*)(ws + off);
  u16t* wqkv_bf = (u16t*)(ws + off + (size_t)T * HID * 2);
  u16t* wo_bf   = hid_bf;  // aliases: hid_bf dead after GEMM1 (stream-ordered)

  // 0) convert f32 operands to bf16 once
  cvt_bf16<<<(T * HID / 8) / 256, 256, 0, stream>>>(hidden, hid_bf, T * HID / 8);
  cvt_bf16<<<(QKV_N * HID / 8) / 256, 256, 0, stream>>>(w_qkv, wqkv_bf, QKV_N * HID / 8);
  // 1) qkv = hidden @ w_qkv^T (256^2 8-phase)
  gemm256<0><<<dim3(QKV_N / 256, T / 256), 512, 0, stream>>>(hid_bf, wqkv_bf, qkv, QKV_N, HID);
  // 1b) convert w_o into the now-dead hid_bf region
  cvt_bf16<<<(HID * HID / 8) / 256, 256, 0, stream>>>(w_o, wo_bf, HID * HID / 8);
  // 2) rope q/k, gate, repack k_global
  prep_kernel<<<T, 256, 0, stream>>>(positions, qkv, k_global, w_gate, b_gate, Qr, Kl, KG, gateb);
  // 3) transpose V's to [g][d][t]
  transpose_gd<0><<<dim3(T / 64, DH / 64, NKV), 256, 0, stream>>>(qkv, VlT, QKV_N, HID + NKV * DH);
  transpose_gd<1><<<dim3(T / 64, DH / 64, NKV), 256, 0, stream>>>(v_global, VGT, NKV * DH, 0);
  // 4) local sliding-window attention -> out_l
  attn_kernel<1><<<dim3(NH, T / 128), 256, 0, stream>>>(Qr, Kl, VlT, nullptr, nullptr, out_l);
  // 5) global causal attention + gate-combine -> out_c
  attn_kernel<0><<<dim3(NH, T / 128), 256, 0, stream>>>(Qr, KG, VGT, gateb, out_l, out_c);
  // 6) final = out_c @ w_o^T (256^2 8-phase)
  gemm256<1><<<dim3(HID / 256, T / 256), 512, 0, stream>>>(out_c, wo_bf, out, HID, HID);
}

// Round 3
// 659.809 us; speedup vs baseline: 1.2688x; 1.0708x over previous
//
#include <hip/hip_runtime.h>
#include <hip/hip_bf16.h>
#include <math.h>

#define T 2048
#define HID 4096
#define NH 32
#define NKV 8
#define DH 128
#define QKV_N 6144
#define SCALE_F 0.08838834764831845f
#define NEGV -1e9f

typedef unsigned short u16t;
typedef __attribute__((ext_vector_type(8))) short bf8;
typedef __attribute__((ext_vector_type(4))) float f4;

__device__ __forceinline__ float bf2f(u16t x) {
  unsigned int u = ((unsigned int)x) << 16;
  return __builtin_bit_cast(float, u);
}
__device__ __forceinline__ u16t f2bf(float f) {
  unsigned int u = __builtin_bit_cast(unsigned int, f);
  u += 0x7fffu + ((u >> 16) & 1u);
  return (u16t)(u >> 16);
}

template <int F32>
__device__ __forceinline__ bf8 load8(const void* p, size_t idx) {
  if (F32) {
    const f4* fp = (const f4*)((const float*)p + idx);
    f4 a = fp[0], b = fp[1];
    bf8 r;
    r[0] = (short)f2bf(a[0]); r[1] = (short)f2bf(a[1]);
    r[2] = (short)f2bf(a[2]); r[3] = (short)f2bf(a[3]);
    r[4] = (short)f2bf(b[0]); r[5] = (short)f2bf(b[1]);
    r[6] = (short)f2bf(b[2]); r[7] = (short)f2bf(b[3]);
    return r;
  }
  return *(const bf8*)((const u16t*)p + idx);
}

// async 16B global -> LDS copy (dest must be linear: wave base + lane*16)
__device__ __forceinline__ void gl_lds16(const u16t* g, u16t* l) {
  __builtin_amdgcn_global_load_lds(
      (const __attribute__((address_space(1))) void*)g,
      (__attribute__((address_space(3))) void*)l, 16, 0, 0);
}

#define BARR() __builtin_amdgcn_s_barrier()
#define LGKM0() asm volatile("s_waitcnt lgkmcnt(0)" ::: "memory")
#define VM4() asm volatile("s_waitcnt vmcnt(4)" ::: "memory")
#define VM2() asm volatile("s_waitcnt vmcnt(2)" ::: "memory")
#define VM0() asm volatile("s_waitcnt vmcnt(0)" ::: "memory")

// ---------------- f32 -> bf16 bulk convert (8 elems/thread) -----------------
__global__ __launch_bounds__(256) void cvt_bf16(const float* __restrict__ in,
                                                u16t* __restrict__ out, int n8) {
  int i = blockIdx.x * 256 + threadIdx.x;
  if (i >= n8) return;
  const f4* fp = (const f4*)(in + (size_t)i * 8);
  f4 a = fp[0], b = fp[1];
  bf8 r;
  r[0] = (short)f2bf(a[0]); r[1] = (short)f2bf(a[1]);
  r[2] = (short)f2bf(a[2]); r[3] = (short)f2bf(a[3]);
  r[4] = (short)f2bf(b[0]); r[5] = (short)f2bf(b[1]);
  r[6] = (short)f2bf(b[2]); r[7] = (short)f2bf(b[3]);
  *(bf8*)(out + (size_t)i * 8) = r;
}

// ---------------- 256x256 8-phase GEMM: C[M][N] = A[M][K] * B[N][K]^T --------
__device__ __forceinline__ void stage_ht(const u16t* __restrict__ G, int K,
                                         int k0, u16t* lds, int tid) {
#pragma unroll
  for (int i = 0; i < 2; i++) {
    int c = tid + 512 * i;
    int r = c >> 3;
    int sc = (c & 7) ^ (r & 7);
    gl_lds16(G + (size_t)r * K + k0 + sc * 8, lds + c * 8);
  }
}

template <int NF, int RS>
__device__ __forceinline__ void ld_fr(bf8 (*f)[2], const u16t* buf, int rb, int quad) {
#pragma unroll
  for (int i = 0; i < NF; i++)
#pragma unroll
    for (int kq = 0; kq < 2; kq++) {
      int r = rb + i * RS;
      int ch = (kq * 4 + quad) ^ (r & 7);
      f[i][kq] = *(const bf8*)&buf[r * 64 + ch * 8];
    }
}

template <int QA, int QB>
__device__ __forceinline__ void mfma_quad(f4 (*acc)[4], const bf8 (*af)[2],
                                          const bf8 (*bf_)[2]) {
#pragma unroll
  for (int m = 0; m < 4; m++)
#pragma unroll
    for (int n = 0; n < 2; n++)
#pragma unroll
      for (int kq = 0; kq < 2; kq++)
        acc[QA * 4 + m][QB * 2 + n] = __builtin_amdgcn_mfma_f32_16x16x32_bf16(
            af[m][kq], bf_[n][kq], acc[QA * 4 + m][QB * 2 + n], 0, 0, 0);
}

template <int OUT32>
__global__ __launch_bounds__(512, 2) void gemm256(const u16t* __restrict__ A,
                                                  const u16t* __restrict__ B,
                                                  void* __restrict__ C, int N, int K) {
  __shared__ alignas(16) u16t As[2][2][128 * 64];
  __shared__ alignas(16) u16t Bs[2][2][128 * 64];
  const int tid = threadIdx.x;
  const int wave = tid >> 6, lane = tid & 63;
  const int l15 = lane & 15, quad = lane >> 4;
  const int wm = wave >> 2, wn = wave & 3;

  unsigned nwg = gridDim.x * gridDim.y;
  unsigned lin = blockIdx.y * gridDim.x + blockIdx.x;
  lin = (lin & 7) * (nwg >> 3) + (lin >> 3);
  const int bx = lin % gridDim.x, by = lin / gridDim.x;
  const int m0 = by * 256, n0 = bx * 256;

  const u16t* A0p = A + (size_t)m0 * K;
  const u16t* A1p = A0p + (size_t)128 * K;
  const u16t* B0p = B + (size_t)n0 * K;
  const u16t* B1p = B0p + (size_t)128 * K;

  const int NT = K >> 6;

  stage_ht(A0p, K, 0, &As[0][0][0], tid);
  stage_ht(B0p, K, 0, &Bs[0][0][0], tid);
  stage_ht(B1p, K, 0, &Bs[0][1][0], tid);
  stage_ht(A1p, K, 0, &As[0][1][0], tid);

  f4 acc[8][4];
#pragma unroll
  for (int i = 0; i < 8; i++)
#pragma unroll
    for (int j = 0; j < 4; j++) acc[i][j] = (f4){0.f, 0.f, 0.f, 0.f};

  VM4();
  BARR();

  bf8 af[4][2], b0f[2][2], b1f[2][2];
  const int ra = wm * 16 + l15;
  const int rb = wn * 16 + l15;

#pragma unroll 1
  for (int t = 0; t < NT; ++t) {
    const int cur = t & 1, nxt = cur ^ 1;
    const int kn = (t + 1) << 6;
    const bool st = (t + 1) < NT;
    // ---- phase 0: (A0, B0); stage A0(t+1)
    ld_fr<4, 32>(af, &As[cur][0][0], ra, quad);
    ld_fr<2, 64>(b0f, &Bs[cur][0][0], rb, quad);
    if (st) stage_ht(A0p, K, kn, &As[nxt][0][0], tid);
    BARR(); LGKM0();
    __builtin_amdgcn_s_setprio(1);
    mfma_quad<0, 0>(acc, af, b0f);
    __builtin_amdgcn_s_setprio(0);
    if (st) { VM4(); } else { VM2(); }
    BARR();
    // ---- phase 1: (A0, B1); stage B0(t+1)
    ld_fr<2, 64>(b1f, &Bs[cur][1][0], rb, quad);
    if (st) stage_ht(B0p, K, kn, &Bs[nxt][0][0], tid);
    BARR(); LGKM0();
    __builtin_amdgcn_s_setprio(1);
    mfma_quad<0, 1>(acc, af, b1f);
    __builtin_amdgcn_s_setprio(0);
    if (st) { VM4(); } else { VM0(); }
    BARR();
    // ---- phase 2: (A1, B1); stage B1(t+1)
    ld_fr<4, 32>(af, &As[cur][1][0], ra, quad);
    if (st) stage_ht(B1p, K, kn, &Bs[nxt][1][0], tid);
    BARR(); LGKM0();
    __builtin_amdgcn_s_setprio(1);
    mfma_quad<1, 1>(acc, af, b1f);
    __builtin_amdgcn_s_setprio(0);
    BARR();
    // ---- phase 3: (A1, B0); stage A1(t+1)
    if (st) stage_ht(A1p, K, kn, &As[nxt][1][0], tid);
    BARR();
    __builtin_amdgcn_s_setprio(1);
    mfma_quad<1, 0>(acc, af, b0f);
    __builtin_amdgcn_s_setprio(0);
    if (st) { VM4(); }
    BARR();
  }

#pragma unroll
  for (int fm = 0; fm < 8; fm++)
#pragma unroll
    for (int fn = 0; fn < 4; fn++)
#pragma unroll
      for (int r = 0; r < 4; r++) {
        int row = m0 + fm * 32 + wm * 16 + quad * 4 + r;
        int col = n0 + fn * 64 + wn * 16 + l15;
        if (OUT32)
          ((float*)C)[(size_t)row * N + col] = acc[fm][fn][r];
        else
          ((u16t*)C)[(size_t)row * N + col] = f2bf(acc[fm][fn][r]);
      }
}

// ---------------- Prep: RoPE q/k, gate, repack k_global ------------------------
__global__ __launch_bounds__(256) void prep_kernel(
    const int* __restrict__ positions, const u16t* __restrict__ qkv,
    const float* __restrict__ kg_in, const float* __restrict__ wg,
    const float* __restrict__ bg, u16t* __restrict__ Qr, u16t* __restrict__ Kl,
    u16t* __restrict__ KG, float* __restrict__ gate) {
  const int t = blockIdx.x, tid = threadIdx.x;
  const float pos = (float)positions[t];
  const u16t* row = qkv + (size_t)t * QKV_N;
  float gp = 0.f;
#pragma unroll
  for (int i = 0; i < 8; i++) {
    int p = tid * 8 + i;
    int h = p >> 6, dp = p & 63;
    float invf = exp2f(-0.20762050593045702f * (float)dp);
    float f = pos * invf;
    float c = cosf(f), s = sinf(f);
    float x1 = bf2f(row[h * DH + dp]);
    float x2 = bf2f(row[h * DH + dp + 64]);
    float o1 = x1 * c - x2 * s;
    float o2 = x2 * c + x1 * s;
    Qr[(size_t)t * HID + h * DH + dp] = f2bf(o1);
    Qr[(size_t)t * HID + h * DH + dp + 64] = f2bf(o2);
    gp += o1 * wg[h * DH + dp] + o2 * wg[h * DH + dp + 64];
  }
  gp += __shfl_xor(gp, 1, 64);
  gp += __shfl_xor(gp, 2, 64);
  gp += __shfl_xor(gp, 4, 64);
  if ((tid & 7) == 0) {
    int h = tid >> 3;
    gate[t * NH + h] = 1.f / (1.f + expf(-(gp + bg[h])));
  }
  const u16t* krow = row + HID;
#pragma unroll
  for (int i = 0; i < 2; i++) {
    int p = tid * 2 + i;
    int g = p >> 6, dp = p & 63;
    float invf = exp2f(-0.20762050593045702f * (float)dp);
    float f = pos * invf;
    float c = cosf(f), s = sinf(f);
    float x1 = bf2f(krow[g * DH + dp]);
    float x2 = bf2f(krow[g * DH + dp + 64]);
    Kl[(size_t)g * T * DH + t * DH + dp] = f2bf(x1 * c - x2 * s);
    Kl[(size_t)g * T * DH + t * DH + dp + 64] = f2bf(x2 * c + x1 * s);
  }
  {
    int d4 = tid * 4;
    int g = d4 >> 7, d = d4 & 127;
    const float* src = kg_in + (size_t)t * (NKV * DH) + d4;
    u16t* dst = KG + (size_t)g * T * DH + t * DH + d;
    dst[0] = f2bf(src[0]); dst[1] = f2bf(src[1]);
    dst[2] = f2bf(src[2]); dst[3] = f2bf(src[3]);
  }
}

// ---------------- Transpose: out[g][d][t] = in[t*istride + coff + g*128 + d] ---
template <int F32>
__global__ __launch_bounds__(256) void transpose_gd(const void* __restrict__ in,
                                                    u16t* __restrict__ out,
                                                    int istride, int coff) {
  __shared__ u16t tile[64][72];
  const int g = blockIdx.z;
  const int t0 = blockIdx.x * 64, d0 = blockIdx.y * 64;
  u16t* dst = out + (size_t)g * DH * T;
  const int tid = threadIdx.x;
#pragma unroll
  for (int i = 0; i < 2; i++) {
    int c = tid + 256 * i;
    int r = c >> 3, dch = (c & 7) << 3;
    size_t idx = (size_t)coff + g * DH + (size_t)(t0 + r) * istride + d0 + dch;
    *(bf8*)&tile[r][dch] = load8<F32>(in, idx);
  }
  __syncthreads();
#pragma unroll
  for (int i = 0; i < 2; i++) {
    int c = tid + 256 * i;
    int d = c >> 3, tch = (c & 7) << 3;
    bf8 v;
#pragma unroll
    for (int j = 0; j < 8; j++) v[j] = tile[tch + j][d];
    *(bf8*)&dst[(size_t)(d0 + d) * T + t0 + tch] = v;
  }
}

// ---------------- Flash attention (LOCAL=1: sliding window; 0: causal+combine) -
// LPT block order (long qt first), async swizzled K/V staging, 2 barriers/iter.
template <int LOCAL>
__global__ __launch_bounds__(256) void attn_kernel(
    const u16t* __restrict__ Qr, const u16t* __restrict__ Kbase,
    const u16t* __restrict__ VTbase, const float* __restrict__ gate,
    const u16t* __restrict__ oL, u16t* __restrict__ outp) {
  __shared__ alignas(16) u16t k_lds[64 * 128];   // [kv][d], XOR chunk-swizzled
  __shared__ alignas(16) u16t v_lds[128 * 64];   // [d][kv], XOR chunk-swizzled
  __shared__ u16t p_lds[128 * 72];               // [q][kv], wave-private rows
  const int h = blockIdx.x;
  const int qt = gridDim.y - 1 - blockIdx.y;     // LPT: longest blocks first
  const int g = h >> 2;
  const int tid = threadIdx.x, wave = tid >> 6, lane = tid & 63;
  const int l15 = lane & 15, quad = lane >> 4;
  const int q0 = qt * 128 + wave * 32;
  const u16t* K = Kbase + (size_t)g * T * DH;    // [t][d]
  const u16t* VT = VTbase + (size_t)g * T * DH;  // [d][t]

  bf8 qf[2][4];
#pragma unroll
  for (int mt = 0; mt < 2; mt++)
#pragma unroll
    for (int kq = 0; kq < 4; kq++)
      qf[mt][kq] = *(const bf8*)&Qr[(size_t)(q0 + mt * 16 + l15) * HID + h * DH + kq * 32 + quad * 8];

  f4 oacc[2][8];
  float m_st[2][4], l_st[2][4];
#pragma unroll
  for (int mt = 0; mt < 2; mt++) {
#pragma unroll
    for (int dt = 0; dt < 8; dt++) oacc[mt][dt] = (f4){0.f, 0.f, 0.f, 0.f};
#pragma unroll
    for (int r = 0; r < 4; r++) { m_st[mt][r] = -__builtin_inff(); l_st[mt][r] = 0.f; }
  }

  const int jend = 2 * qt + 2;
  const int jbeg = LOCAL ? (qt > 0 ? 2 * qt - 1 : 0) : 0;
  for (int j = jbeg; j < jend; j++) {
    const int kv0 = j * 64;
    __syncthreads();  // all waves done reading k_lds/v_lds of prev iter
    // async staging, both-sides XOR chunk swizzle (K: 16 chunks/row; V: 8)
#pragma unroll
    for (int i = 0; i < 4; i++) {
      int c = tid + 256 * i;
      int rk = c >> 4, ck = c & 15;
      gl_lds16(K + (size_t)(kv0 + rk) * DH + ((ck ^ (rk & 15)) << 3), &k_lds[c * 8]);
      int rv = c >> 3, cv = c & 7;
      gl_lds16(VT + (size_t)rv * T + kv0 + ((cv ^ (rv & 7)) << 3), &v_lds[c * 8]);
    }
    __syncthreads();  // vmcnt(0) drain + barrier
    // S = Q K^T  (per wave: 32 q rows x 64 kv)
    f4 s[2][4];
    __builtin_amdgcn_s_setprio(1);
#pragma unroll
    for (int nt = 0; nt < 4; nt++) {
      bf8 kb[4];
#pragma unroll
      for (int kq = 0; kq < 4; kq++) {
        int rr = nt * 16 + l15;
        kb[kq] = *(const bf8*)&k_lds[rr * 128 + (((kq * 4 + quad) ^ (rr & 15)) << 3)];
      }
#pragma unroll
      for (int mt = 0; mt < 2; mt++) {
        f4 a = (f4){0.f, 0.f, 0.f, 0.f};
#pragma unroll
        for (int kq = 0; kq < 4; kq++)
          a = __builtin_amdgcn_mfma_f32_16x16x32_bf16(qf[mt][kq], kb[kq], a, 0, 0, 0);
        s[mt][nt] = a;
      }
    }
    __builtin_amdgcn_s_setprio(0);
    // scale + mask (skip compare loop on fully-unmasked tiles; wave-uniform)
    const bool full = LOCAL ? false : (kv0 + 63 <= q0);
    if (full) {
#pragma unroll
      for (int mt = 0; mt < 2; mt++)
#pragma unroll
        for (int nt = 0; nt < 4; nt++)
#pragma unroll
          for (int r = 0; r < 4; r++) s[mt][nt][r] *= SCALE_F;
    } else {
#pragma unroll
      for (int mt = 0; mt < 2; mt++)
#pragma unroll
        for (int nt = 0; nt < 4; nt++)
#pragma unroll
          for (int r = 0; r < 4; r++) {
            float v = s[mt][nt][r] * SCALE_F;
            int qq = q0 + mt * 16 + quad * 4 + r;
            int kk = kv0 + nt * 16 + l15;
            bool ok = LOCAL ? (kk <= qq && kk >= qq - 63) : (kk <= qq);
            s[mt][nt][r] = ok ? v : NEGV;
          }
    }
    // online softmax stats
    float alpha[2][4], mn[2][4], rs[2][4];
#pragma unroll
    for (int mt = 0; mt < 2; mt++)
#pragma unroll
      for (int r = 0; r < 4; r++) {
        float rm = fmaxf(fmaxf(s[mt][0][r], s[mt][1][r]), fmaxf(s[mt][2][r], s[mt][3][r]));
        rm = fmaxf(rm, __shfl_xor(rm, 1, 64));
        rm = fmaxf(rm, __shfl_xor(rm, 2, 64));
        rm = fmaxf(rm, __shfl_xor(rm, 4, 64));
        rm = fmaxf(rm, __shfl_xor(rm, 8, 64));
        float m2 = fmaxf(m_st[mt][r], rm);
        alpha[mt][r] = __expf(m_st[mt][r] - m2);
        m_st[mt][r] = m2;
        mn[mt][r] = m2;
        rs[mt][r] = 0.f;
      }
#pragma unroll
    for (int mt = 0; mt < 2; mt++)
#pragma unroll
      for (int nt = 0; nt < 4; nt++)
#pragma unroll
        for (int r = 0; r < 4; r++) {
          float p = __expf(s[mt][nt][r] - mn[mt][r]);
          rs[mt][r] += p;
          p_lds[(wave * 32 + mt * 16 + quad * 4 + r) * 72 + nt * 16 + l15] = f2bf(p);
        }
#pragma unroll
    for (int mt = 0; mt < 2; mt++)
#pragma unroll
      for (int r = 0; r < 4; r++) {
        float t0 = rs[mt][r];
        t0 += __shfl_xor(t0, 1, 64);
        t0 += __shfl_xor(t0, 2, 64);
        t0 += __shfl_xor(t0, 4, 64);
        t0 += __shfl_xor(t0, 8, 64);
        l_st[mt][r] = l_st[mt][r] * alpha[mt][r] + t0;
      }
#pragma unroll
    for (int mt = 0; mt < 2; mt++)
#pragma unroll
      for (int dt = 0; dt < 8; dt++) {
        f4 o = oacc[mt][dt];
        o[0] *= alpha[mt][0]; o[1] *= alpha[mt][1];
        o[2] *= alpha[mt][2]; o[3] *= alpha[mt][3];
        oacc[mt][dt] = o;
      }
    // NO barrier: p_lds rows are wave-private (write+read same wave slice);
    // v_lds was staged behind this iteration's post-stage barrier.
    bf8 pa[2][2];
#pragma unroll
    for (int mt = 0; mt < 2; mt++)
#pragma unroll
      for (int kq = 0; kq < 2; kq++)
        pa[mt][kq] = *(const bf8*)&p_lds[(wave * 32 + mt * 16 + l15) * 72 + kq * 32 + quad * 8];
    __builtin_amdgcn_s_setprio(1);
#pragma unroll
    for (int dt = 0; dt < 8; dt++) {
      bf8 vb[2];
#pragma unroll
      for (int kq = 0; kq < 2; kq++) {
        int rr = dt * 16 + l15;
        vb[kq] = *(const bf8*)&v_lds[rr * 64 + (((kq * 4 + quad) ^ (rr & 7)) << 3)];
      }
#pragma unroll
      for (int mt = 0; mt < 2; mt++) {
        oacc[mt][dt] = __builtin_amdgcn_mfma_f32_16x16x32_bf16(pa[mt][0], vb[0], oacc[mt][dt], 0, 0, 0);
        oacc[mt][dt] = __builtin_amdgcn_mfma_f32_16x16x32_bf16(pa[mt][1], vb[1], oacc[mt][dt], 0, 0, 0);
      }
    }
    __builtin_amdgcn_s_setprio(0);
  }
  // epilogue
#pragma unroll
  for (int mt = 0; mt < 2; mt++)
#pragma unroll
    for (int r = 0; r < 4; r++) {
      int tq = q0 + mt * 16 + quad * 4 + r;
      float inv_l = 1.f / l_st[mt][r];
      if (LOCAL) {
#pragma unroll
        for (int dt = 0; dt < 8; dt++) {
          int col = dt * 16 + l15;
          outp[(size_t)tq * HID + h * DH + col] = f2bf(oacc[mt][dt][r] * inv_l);
        }
      } else {
        float gt = gate[tq * NH + h];
#pragma unroll
        for (int dt = 0; dt < 8; dt++) {
          int col = dt * 16 + l15;
          float ov = oacc[mt][dt][r] * inv_l;
          float ol = bf2f(oL[(size_t)tq * HID + h * DH + col]);
          outp[(size_t)tq * HID + h * DH + col] = f2bf(ov * gt + ol * (1.f - gt));
        }
      }
    }
}

extern "C" void kernel_launch(void* const* d_in, const int* in_sizes, int n_in,
                              void* d_out, int out_size, void* d_ws, size_t ws_size,
                              hipStream_t stream) {
  (void)in_sizes; (void)n_in; (void)out_size; (void)ws_size;
  const int* positions = (const int*)d_in[0];
  const float* hidden = (const float*)d_in[1];
  const float* k_global = (const float*)d_in[2];
  const void* v_global = d_in[3];
  const float* w_qkv = (const float*)d_in[4];
  const float* w_o = (const float*)d_in[5];
  const float* w_gate = (const float*)d_in[6];
  const float* b_gate = (const float*)d_in[7];
  float* out = (float*)d_out;

  char* ws = (char*)d_ws;
  size_t off = 0;
  u16t* qkv = (u16t*)(ws + off); off += (size_t)T * QKV_N * 2;
  u16t* Qr  = (u16t*)(ws + off); off += (size_t)T * HID * 2;
  u16t* Kl  = (u16t*)(ws + off); off += (size_t)NKV * T * DH * 2;
  u16t* KG  = (u16t*)(ws + off); off += (size_t)NKV * T * DH * 2;
  u16t* VlT = (u16t*)(ws + off); off += (size_t)NKV * T * DH * 2;
  u16t* VGT = (u16t*)(ws + off); off += (size_t)NKV * T * DH * 2;
  float* gateb = (float*)(ws + off); off += (size_t)T * NH * 4;
  u16t* out_l = (u16t*)(ws + off); off += (size_t)T * HID * 2;
  u16t* out_c = (u16t*)(ws + off); off += (size_t)T * HID * 2;
  u16t* hid_bf  = (u16t*)(ws + off);
  u16t* wqkv_bf = (u16t*)(ws + off + (size_t)T * HID * 2);
  u16t* wo_bf   = hid_bf;  // aliases: hid_bf dead after GEMM1 (stream-ordered)

  // 0) convert f32 operands to bf16 once
  cvt_bf16<<<(T * HID / 8) / 256, 256, 0, stream>>>(hidden, hid_bf, T * HID / 8);
  cvt_bf16<<<(QKV_N * HID / 8) / 256, 256, 0, stream>>>(w_qkv, wqkv_bf, QKV_N * HID / 8);
  // 1) qkv = hidden @ w_qkv^T (256^2 8-phase)
  gemm256<0><<<dim3(QKV_N / 256, T / 256), 512, 0, stream>>>(hid_bf, wqkv_bf, qkv, QKV_N, HID);
  // 1b) convert w_o into the now-dead hid_bf region
  cvt_bf16<<<(HID * HID / 8) / 256, 256, 0, stream>>>(w_o, wo_bf, HID * HID / 8);
  // 2) rope q/k, gate, repack k_global
  prep_kernel<<<T, 256, 0, stream>>>(positions, qkv, k_global, w_gate, b_gate, Qr, Kl, KG, gateb);
  // 3) transpose V's to [g][d][t]
  transpose_gd<0><<<dim3(T / 64, DH / 64, NKV), 256, 0, stream>>>(qkv, VlT, QKV_N, HID + NKV * DH);
  transpose_gd<1><<<dim3(T / 64, DH / 64, NKV), 256, 0, stream>>>(v_global, VGT, NKV * DH, 0);
  // 4) local sliding-window attention -> out_l
  attn_kernel<1><<<dim3(NH, T / 128), 256, 0, stream>>>(Qr, Kl, VlT, nullptr, nullptr, out_l);
  // 5) global causal attention + gate-combine -> out_c
  attn_kernel<0><<<dim3(NH, T / 128), 256, 0, stream>>>(Qr, KG, VGT, gateb, out_l, out_c);
  // 6) final = out_c @ w_o^T (256^2 8-phase)
  gemm256<1><<<dim3(HID / 256, T / 256), 512, 0, stream>>>(out_c, wo_bf, out, HID, HID);
}